// Round 5
// baseline (222.634 us; speedup 1.0000x reference)
//
#include <hip/hip_runtime.h>
#include <math.h>

#define B     4096
#define ND    13
#define NS    26
#define NF    39
#define VOCAB 100000
#define NP    351      // l<=m pairs in 26x26
#define NPP   360      // padded to 8 chunks * 45
#define CHP   45       // p's per chunk
#define GSTR  28       // Gst row: [0..25]=Gs_j, [26]=A1s, [27]=lut bits
#define RPB   8
#define TPB   512
#define XSS   212

// ---------------- workspace layout (floats) ----------------
#define OFF_GST 0        // 360*28 = 10080
#define OFF_CST 10080    // 1
#define OFF_C2J 10088    // 26
#define OFF_LUT 10120    // 360 ints

// ---- single merged precompute kernel, 28 independent blocks ----
__global__ __launch_bounds__(256) void k_pre(const float* __restrict__ W0,
                                             const float* __restrict__ W1,
                                             const float* __restrict__ b0,
                                             const float* __restrict__ b1,
                                             const float* __restrict__ clw,
                                             float* __restrict__ Gst,
                                             float* __restrict__ cst,
                                             float* __restrict__ c2j,
                                             int* __restrict__ lutg) {
    int blk = blockIdx.x, tid = threadIdx.x;
    if (blk < 26) {
        int j = blk;
        __shared__ float vh[2][128];
        __shared__ float vj[128];
        __shared__ float c2r[2];
        {
            int i = tid & 127, h = tid >> 7;
            const float* wp = W1 + (long)(h * 64) * 3328 + i * 26 + j;
            float acc = 0.f;
#pragma unroll 8
            for (int o = 0; o < 64; o++) acc += clw[128 + h * 64 + o] * wp[o * 3328];
            vh[h][i] = acc;
        }
        __syncthreads();
        if (tid < 128) {
            float vv = vh[0][tid] + vh[1][tid];
            vj[tid] = vv;
            float c = vv * b0[tid];
            for (int off = 32; off; off >>= 1) c += __shfl_down(c, off, 64);
            if ((tid & 63) == 0) c2r[tid >> 6] = c;
        }
        __syncthreads();
        if (tid == 0) c2j[j] = c2r[0] + c2r[1];
        for (int p = tid; p < NPP; p += 256) {
            float g = 0.f;
            if (p < NP) {
                int l = 0, rem = p;
                while (rem >= NS - l) { rem -= NS - l; l++; }
                int m = l + rem;
                float sym = (l != m) ? 1.f : 0.f;
                const float* wa = W0 + l * 26 + m;
                const float* wb = W0 + m * 26 + l;
#pragma unroll 8
                for (int i = 0; i < 128; i++)
                    g += vj[i] * (wa[i * 676] + sym * wb[i * 676]);
            }
            Gst[p * GSTR + j] = g;
        }
    } else if (blk == 26) {
        for (int p = tid; p < NPP; p += 256) {
            float a = 0.f; int lmbits = 0;
            if (p < NP) {
                int l = 0, rem = p;
                while (rem >= NS - l) { rem -= NS - l; l++; }
                int m = l + rem;
                float sym = (l != m) ? 1.f : 0.f;
                const float* wa = W0 + l * 26 + m;
                const float* wb = W0 + m * 26 + l;
#pragma unroll 8
                for (int o = 0; o < 128; o++)
                    a += clw[o] * (wa[o * 676] + sym * wb[o * 676]);
                lmbits = (l << 5) | m;
            }
            Gst[p * GSTR + 26] = a;
            Gst[p * GSTR + 27] = __int_as_float(lmbits);
            lutg[p] = lmbits;
        }
    } else {
        __shared__ float red[2];
        float c = 0.f;
        if (tid < 128) {
            c = clw[tid] * b0[tid] + clw[128 + tid] * b1[tid];
            for (int off = 32; off; off >>= 1) c += __shfl_down(c, off, 64);
            if ((tid & 63) == 0) red[tid >> 6] = c;
        }
        __syncthreads();
        if (tid == 0) cst[0] = 8.f * (red[0] + red[1]);
    }
}

// ---- fused main: 8 rows/block, 512 threads ----
// P1 runs CIN (waves 0-3, 2 chunks each, SGPR LUT) CONCURRENTLY with
// Layer1 (waves 4-7, full-K per thread, weight read once/block, no combine).
// L3+L4+output collapsed into one wave-reduce phase. 6 barriers total.
__global__ __launch_bounds__(512, 4) void k_main(
    const float* __restrict__ inputs, const float* __restrict__ tables,
    const float* __restrict__ lW, const float* __restrict__ lb,
    const float* __restrict__ Gst, const float* __restrict__ c2j,
    const float* __restrict__ cst, const int* __restrict__ lutg,
    const float* __restrict__ dW1, const float* __restrict__ db1,
    const float* __restrict__ dW2, const float* __restrict__ db2,
    const float* __restrict__ dW3, const float* __restrict__ db3,
    const float* __restrict__ dW4, const float* __restrict__ db4,
    const float* __restrict__ clb,
    float* __restrict__ out) {
    __shared__ float xs[RPB][XSS];           // emb per row, CIN layout (6784 B)
    __shared__ float inTf[221 * 8];          // DNN input transposed (7072 B); h2T aliased
    __shared__ float h1Tf[256 * 12];         // stride 12 (12288 B)
    __shared__ float4 pbuf4[1024];           // split-K partials L2/L3 (16 KB)
    __shared__ float lin_s[RPB];
    __shared__ float redbuf[4][RPB];

    float* h2Tf = inTf;                      // alias: inT dead after P1
    float* pbufF = (float*)pbuf4;

    int tid = threadIdx.x;
    int b0r = blockIdx.x * RPB;

    // ---- P0: gather embeddings (16B/thread, 416 threads) + linear term ----
    if (tid < 416) {
        int r = tid / 52, t2 = tid - r * 52;
        int f = t2 >> 1, hf = t2 & 1;
        int idx = (int)inputs[(b0r + r) * NF + ND + f];
        const float4* src = (const float4*)(tables + ((long)f * VOCAB + idx) * 8);
        *(float4*)&xs[r][f * 8 + hf * 4] = src[hf];
    }
    if (tid >= 448 && tid < 448 + RPB) {
        int r = tid - 448;
        float acc = lb[0];
        for (int c = 0; c < NF; c++) acc += inputs[(b0r + r) * NF + c] * lW[c];
        lin_s[r] = acc;
    }
    __syncthreads();

    // ---- P0.5: build transposed DNN input (dense cols direct from global) ----
    for (int e = tid; e < 221 * 8; e += TPB) {
        int c = e >> 3, r = e & 7;
        inTf[c * 8 + r] = (c < ND) ? inputs[(b0r + r) * NF + c] : xs[r][c - ND];
    }
    __syncthreads();

    // ---- P1: CIN (waves 0-3) || Layer1 221->256 (waves 4-7) ----
    {
        int w = tid >> 6;
        int wu = __builtin_amdgcn_readfirstlane(w);
        int lane = tid & 63;
        if (wu < 4) {
            // CIN: wave wu handles chunks 2wu, 2wu+1; lane=(row,k)
            int row = lane >> 3, k = lane & 7;
            const float* xrow = &xs[row][0];
            float t[27];
#pragma unroll
            for (int j = 0; j < 27; j++) t[j] = 0.f;
#pragma unroll 1
            for (int half = 0; half < 2; half++) {
                int ch = 2 * wu + half;
                const float4* g4 = (const float4*)Gst + ch * CHP * 7;
                const int* lu = lutg + ch * CHP;
#pragma unroll 5
                for (int pi = 0; pi < CHP; pi++) {
                    int lm = lu[pi];                       // uniform -> s_load, chain-free
                    float q = xrow[(lm >> 5) * 8 + k] * xrow[(lm & 31) * 8 + k];
                    float4 g0 = g4[pi * 7 + 0], g1 = g4[pi * 7 + 1];
                    float4 g2 = g4[pi * 7 + 2], g3 = g4[pi * 7 + 3];
                    float4 g4v = g4[pi * 7 + 4], g5 = g4[pi * 7 + 5];
                    float4 g6 = g4[pi * 7 + 6];
                    t[0]  += g0.x * q; t[1]  += g0.y * q; t[2]  += g0.z * q; t[3]  += g0.w * q;
                    t[4]  += g1.x * q; t[5]  += g1.y * q; t[6]  += g1.z * q; t[7]  += g1.w * q;
                    t[8]  += g2.x * q; t[9]  += g2.y * q; t[10] += g2.z * q; t[11] += g2.w * q;
                    t[12] += g3.x * q; t[13] += g3.y * q; t[14] += g3.z * q; t[15] += g3.w * q;
                    t[16] += g4v.x * q; t[17] += g4v.y * q; t[18] += g4v.z * q; t[19] += g4v.w * q;
                    t[20] += g5.x * q; t[21] += g5.y * q; t[22] += g5.z * q; t[23] += g5.w * q;
                    t[24] += g6.x * q; t[25] += g6.y * q; t[26] += g6.z * q;
                }
            }
            float csel = (wu == 0) ? 1.f : 0.f;
            float part = t[26];
#pragma unroll
            for (int j = 0; j < 26; j++) {
                float xv = xrow[j * 8 + k];
                part += (t[j] + csel * c2j[j]) * xv;
            }
            part += __shfl_xor(part, 1, 64);
            part += __shfl_xor(part, 2, 64);
            part += __shfl_xor(part, 4, 64);
            if (k == 0) redbuf[wu][row] = part;
        } else {
            // Layer1: o = tid-256, full K, 8 rows, weight read once per block
            int o = tid & 255;
            float4 S0 = make_float4(0.f, 0.f, 0.f, 0.f);
            float4 S1 = S0;
#pragma unroll 4
            for (int c = 0; c < 221; c++) {
                float wv = dW1[c * 256 + o];
                float4 i0 = *(const float4*)&inTf[c * 8];
                float4 i1 = *(const float4*)&inTf[c * 8 + 4];
                S0.x += i0.x * wv; S0.y += i0.y * wv; S0.z += i0.z * wv; S0.w += i0.w * wv;
                S1.x += i1.x * wv; S1.y += i1.y * wv; S1.z += i1.z * wv; S1.w += i1.w * wv;
            }
            float bb = db1[o];
            S0.x = fmaxf(S0.x + bb, 0.f); S0.y = fmaxf(S0.y + bb, 0.f);
            S0.z = fmaxf(S0.z + bb, 0.f); S0.w = fmaxf(S0.w + bb, 0.f);
            S1.x = fmaxf(S1.x + bb, 0.f); S1.y = fmaxf(S1.y + bb, 0.f);
            S1.z = fmaxf(S1.z + bb, 0.f); S1.w = fmaxf(S1.w + bb, 0.f);
            *(float4*)&h1Tf[o * 12]     = S0;
            *(float4*)&h1Tf[o * 12 + 4] = S1;
        }
    }
    __syncthreads();

    // ---- P2: Layer2 256->128, split-K x4, all 512 threads ----
    {
        int o = tid & 127, cg = tid >> 7;
        int c0 = cg << 6;
        float4 A0 = make_float4(0.f, 0.f, 0.f, 0.f);
        float4 A1 = A0;
#pragma unroll 4
        for (int cc = 0; cc < 64; cc++) {
            int c = c0 + cc;
            float wv = dW2[c * 128 + o];
            float4 i0 = *(const float4*)&h1Tf[c * 12];
            float4 i1 = *(const float4*)&h1Tf[c * 12 + 4];
            A0.x += i0.x * wv; A0.y += i0.y * wv; A0.z += i0.z * wv; A0.w += i0.w * wv;
            A1.x += i1.x * wv; A1.y += i1.y * wv; A1.z += i1.z * wv; A1.w += i1.w * wv;
        }
        int pb = (cg * 128 + o) * 2;
        pbuf4[pb]     = A0;
        pbuf4[pb + 1] = A1;
    }
    __syncthreads();

    // ---- P3: Layer2 combine + relu -> h2 (aliased over inT) ----
    if (tid < 128) {
        int o = tid;
        float bb = db2[o];
        float sx0 = bb, sy0 = bb, sz0 = bb, sw0 = bb;
        float sx1 = bb, sy1 = bb, sz1 = bb, sw1 = bb;
#pragma unroll
        for (int cg = 0; cg < 4; cg++) {
            float4 p0 = pbuf4[(cg * 128 + o) * 2];
            float4 p1 = pbuf4[(cg * 128 + o) * 2 + 1];
            sx0 += p0.x; sy0 += p0.y; sz0 += p0.z; sw0 += p0.w;
            sx1 += p1.x; sy1 += p1.y; sz1 += p1.z; sw1 += p1.w;
        }
        float4 S0, S1;
        S0.x = fmaxf(sx0, 0.f); S0.y = fmaxf(sy0, 0.f);
        S0.z = fmaxf(sz0, 0.f); S0.w = fmaxf(sw0, 0.f);
        S1.x = fmaxf(sx1, 0.f); S1.y = fmaxf(sy1, 0.f);
        S1.z = fmaxf(sz1, 0.f); S1.w = fmaxf(sw1, 0.f);
        *(float4*)&h2Tf[o * 12]     = S0;
        *(float4*)&h2Tf[o * 12 + 4] = S1;
    }
    __syncthreads();

    // ---- P4: Layer3 128->64, split-K x8 ----
    {
        int o = tid & 63, cg = tid >> 6;
        int c0 = cg << 4;
        float4 A0 = make_float4(0.f, 0.f, 0.f, 0.f);
        float4 A1 = A0;
#pragma unroll 8
        for (int cc = 0; cc < 16; cc++) {
            int c = c0 + cc;
            float wv = dW3[c * 64 + o];
            float4 i0 = *(const float4*)&h2Tf[c * 12];
            float4 i1 = *(const float4*)&h2Tf[c * 12 + 4];
            A0.x += i0.x * wv; A0.y += i0.y * wv; A0.z += i0.z * wv; A0.w += i0.w * wv;
            A1.x += i1.x * wv; A1.y += i1.y * wv; A1.z += i1.z * wv; A1.w += i1.w * wv;
        }
        int pb = (cg * 64 + o) * 2;
        pbuf4[pb]     = A0;
        pbuf4[pb + 1] = A1;
    }
    __syncthreads();

    // ---- P5: L3 combine + L4 + final + sigmoid. lane=o, wave=r ----
    {
        int r = tid >> 6, o = tid & 63;
        float s = 0.f;
#pragma unroll
        for (int cg = 0; cg < 8; cg++)
            s += pbufF[(cg * 64 + o) * 8 + r];
        float h3 = fmaxf(s + db3[o], 0.f) * dW4[o];
        h3 += __shfl_xor(h3, 1, 64);
        h3 += __shfl_xor(h3, 2, 64);
        h3 += __shfl_xor(h3, 4, 64);
        h3 += __shfl_xor(h3, 8, 64);
        h3 += __shfl_xor(h3, 16, 64);
        h3 += __shfl_xor(h3, 32, 64);
        if (o == 0) {
            float scin = cst[0];
#pragma unroll
            for (int w = 0; w < 4; w++) scin += redbuf[w][r];
            float dense = fmaxf(h3 + db4[0], 0.f);
            float cin = fmaxf(scin + clb[0], 0.f);
            float x = lin_s[r] + cin + dense;
            out[b0r + r] = 1.f / (1.f + expf(-x));
        }
    }
}

extern "C" void kernel_launch(void* const* d_in, const int* in_sizes, int n_in,
                              void* d_out, int out_size, void* d_ws, size_t ws_size,
                              hipStream_t stream) {
    const float* inputs = (const float*)d_in[0];
    const float* tables = (const float*)d_in[1];
    const float* lW     = (const float*)d_in[2];
    const float* lb     = (const float*)d_in[3];
    const float* W0     = (const float*)d_in[4];
    const float* b0     = (const float*)d_in[5];
    const float* W1c    = (const float*)d_in[6];
    const float* b1c    = (const float*)d_in[7];
    const float* clw    = (const float*)d_in[8];
    const float* clb    = (const float*)d_in[9];
    const float* dW1    = (const float*)d_in[10];
    const float* db1    = (const float*)d_in[11];
    const float* dW2    = (const float*)d_in[12];
    const float* db2    = (const float*)d_in[13];
    const float* dW3    = (const float*)d_in[14];
    const float* db3    = (const float*)d_in[15];
    const float* dW4    = (const float*)d_in[16];
    const float* db4    = (const float*)d_in[17];

    float* ws   = (float*)d_ws;
    float* Gst  = ws + OFF_GST;
    float* cst  = ws + OFF_CST;
    float* c2j  = ws + OFF_C2J;
    int*   lutg = (int*)(ws + OFF_LUT);

    k_pre<<<28, 256, 0, stream>>>(W0, W1c, b0, b1c, clw, Gst, cst, c2j, lutg);
    k_main<<<B / RPB, TPB, 0, stream>>>(inputs, tables, lW, lb, Gst, c2j, cst, lutg,
                                        dW1, db1, dW2, db2, dW3, db3, dW4, db4, clb,
                                        (float*)d_out);
}